// Round 5
// baseline (179.738 us; speedup 1.0000x reference)
//
#include <hip/hip_runtime.h>

// LengthRegulator: out[b, t, :] = x[b, j, :] where j = searchsorted(cumsum(dur[b]), t, 'right'),
// zero for t >= total duration. B=16, L=512, D=512, T_MAX=4096. fp32 in/out.
//
// R10: DURATION PROBE — launch the identical kernel TWICE (idempotent: second pass
//  rewrites the same values; absmax stays 0). dur_us(R10) - dur_us(R9) ~= one
//  steady-state kernel duration, which rocprof's top-5 never shows (all slots taken
//  by the ~80-85 us harness poison fills; our kernel is known only to be < 80 us).
//  R7 (load ILP), R8 (prologue), R9 (nt->plain stores) were ALL neutral (161/158/154);
//  model says kernel ~30 us vs 24 us BW floor => ROOFLINE, but that's unmeasured.
//  If delta ~25-30 us: resubmit single-launch R9 and declare roofline with arithmetic.
//  If delta ~60-70 us: kernel is throughput-limited at ~2 TB/s and there is real
//  headroom none of the latency levers touched.
//  Kernel body = R9 unchanged (best measured: 154.5 us).

#define BATCH 16
#define LTOK  512
#define DIM   512
#define TMAX  4096
#define ROWS  16          // output rows per block; 256 thr = 2 row-halves x 128 lanes

typedef float f4v __attribute__((ext_vector_type(4)));  // 16B, same layout as float4

__global__ __launch_bounds__(256) void MRTE_fused_kernel(const float* __restrict__ x,
                                                         const int* __restrict__ dur,
                                                         float* __restrict__ out) {
    __shared__ int stok[ROWS];   // token index per block row
    __shared__ int stotal;       // total frames for this batch
    const int b    = blockIdx.y;
    const int t0   = blockIdx.x * ROWS;
    const int tid  = threadIdx.x;
    const int half = tid >> 7;   // 0/1: rows 0-7 vs 8-15
    const int lane = tid & 127;  // 16B column (128 * 16B = 2KB row)

    // ---- wave 0: scan of dur[b][0..511] entirely in registers + direct tok compute ----
    if (tid < 64) {
        const int4* __restrict__ d4 = reinterpret_cast<const int4*>(dur + b * LTOK);
        int4 a = d4[tid * 2];
        int4 c = d4[tid * 2 + 1];
        int p0 = a.x;
        int p1 = p0 + a.y;
        int p2 = p1 + a.z;
        int p3 = p2 + a.w;
        int p4 = p3 + c.x;
        int p5 = p4 + c.y;
        int p6 = p5 + c.z;
        int p7 = p6 + c.w;
        int s = p7;
        #pragma unroll
        for (int off = 1; off < 64; off <<= 1) {   // 64-lane inclusive shfl scan
            int n = __shfl_up(s, off, 64);
            if (tid >= off) s += n;
        }
        const int base = s - p7;                    // exclusive prefix of this lane's chunk
        // lane holds cumsum ends for tokens 8*tid .. 8*tid+7:
        const int e0 = base + p0, e1 = base + p1, e2 = base + p2, e3 = base + p3;
        const int e4 = base + p4, e5 = base + p5, e6 = base + p6, e7 = base + p7;
        const int tot = __shfl(s, 63, 64);
        if (tid == 63) stotal = s;

        if (t0 < tot) {
            // j(t) = #{ends <= t} summed over all 512 ends.
            // Pack two row-counts per 32-bit reg (sums <= 512, no field overflow).
            unsigned pk[8];
            #pragma unroll
            for (int rp = 0; rp < 8; ++rp) {
                const int ta = t0 + 2 * rp;
                const int tb = ta + 1;
                unsigned ca = (unsigned)((e0 <= ta) + (e1 <= ta) + (e2 <= ta) + (e3 <= ta) +
                                         (e4 <= ta) + (e5 <= ta) + (e6 <= ta) + (e7 <= ta));
                unsigned cb = (unsigned)((e0 <= tb) + (e1 <= tb) + (e2 <= tb) + (e3 <= tb) +
                                         (e4 <= tb) + (e5 <= tb) + (e6 <= tb) + (e7 <= tb));
                unsigned p = ca | (cb << 16);
                #pragma unroll
                for (int off = 32; off >= 1; off >>= 1)
                    p += (unsigned)__shfl_xor((int)p, off, 64);
                pk[rp] = p;
            }
            if (tid == 0) {
                #pragma unroll
                for (int rp = 0; rp < 8; ++rp) {
                    stok[2 * rp]     = (int)(pk[rp] & 0xffffu);
                    stok[2 * rp + 1] = (int)(pk[rp] >> 16);
                }
            }
        }
    }
    __syncthreads();

    const int total = stotal;
    f4v* __restrict__ ob =
        reinterpret_cast<f4v*>(out + ((size_t)b * TMAX + (size_t)t0) * DIM);

    // ---- fast path: block entirely in the zero tail -> plain streaming zero-fill ----
    if (t0 >= total) {
        #pragma unroll
        for (int i = 0; i < 8; ++i)
            ob[(size_t)(half * 8 + i) * (DIM / 4) + lane] = (f4v)0.f;
        return;
    }

    const f4v* __restrict__ xb =
        reinterpret_cast<const f4v*>(x + (size_t)b * LTOK * DIM);
    const int tbase = t0 + half * 8;

    // phase 1: all 8 token indices (LDS broadcast reads, independent)
    int j[8];
    #pragma unroll
    for (int i = 0; i < 8; ++i)
        j[i] = (tbase + i < total) ? stok[half * 8 + i] : -1;

    // phase 2: independent gather loads + plain stores
    #pragma unroll
    for (int i = 0; i < 8; ++i) {
        f4v v = (f4v)0.f;
        if (j[i] >= 0) v = xb[(size_t)j[i] * (DIM / 4) + lane];
        ob[(size_t)(half * 8 + i) * (DIM / 4) + lane] = v;
    }
}

extern "C" void kernel_launch(void* const* d_in, const int* in_sizes, int n_in,
                              void* d_out, int out_size, void* d_ws, size_t ws_size,
                              hipStream_t stream) {
    const float* x   = (const float*)d_in[0];        // [B, L, D] fp32
    const int*   dur = (const int*)d_in[1];          // [B, L] int32
    // d_in[2] = mel_max_length scalar (static 4096; hard-coded)
    float* out = (float*)d_out;                       // [B, TMAX, D] fp32

    // DURATION PROBE: two identical launches. Second is idempotent (same values
    // rewritten); marginal dur_us vs R9 ~= one steady-state kernel duration.
    MRTE_fused_kernel<<<dim3(TMAX / ROWS, BATCH), 256, 0, stream>>>(x, dur, out);
    MRTE_fused_kernel<<<dim3(TMAX / ROWS, BATCH), 256, 0, stream>>>(x, dur, out);
}

// Round 6
// 155.565 us; speedup vs baseline: 1.1554x; 1.1554x over previous
//
#include <hip/hip_runtime.h>

// LengthRegulator: out[b, t, :] = x[b, j, :] where j = searchsorted(cumsum(dur[b]), t, 'right'),
// zero for t >= total duration. B=16, L=512, D=512, T_MAX=4096. fp32 in/out.
//
// R11 = R9 restored (single launch). FINAL.
//  R10's double-launch duration probe measured the kernel at ~25.2 us marginal
//  (179.7 - 154.5). Traffic = 134 MB write + ~17 MB read = 151 MB => ~6.0 TB/s,
//  93-95% of the 6.4-6.5 TB/s ceiling the harness's own fillBuffer demonstrates
//  on this chip. Memory-bound roofline reached; the other ~130 us of dur_us is
//  the ~84 us harness poison fill + ~45 us fixed small-dispatch overhead.
//  History: R7 load-ILP neutral, R8 prologue-elimination neutral, R9 nt->plain
//  stores best (154.5), R10 probe. All consistent with a BW-bound ~25 us kernel.

#define BATCH 16
#define LTOK  512
#define DIM   512
#define TMAX  4096
#define ROWS  16          // output rows per block; 256 thr = 2 row-halves x 128 lanes

typedef float f4v __attribute__((ext_vector_type(4)));  // 16B, same layout as float4

__global__ __launch_bounds__(256) void MRTE_fused_kernel(const float* __restrict__ x,
                                                         const int* __restrict__ dur,
                                                         float* __restrict__ out) {
    __shared__ int stok[ROWS];   // token index per block row
    __shared__ int stotal;       // total frames for this batch
    const int b    = blockIdx.y;
    const int t0   = blockIdx.x * ROWS;
    const int tid  = threadIdx.x;
    const int half = tid >> 7;   // 0/1: rows 0-7 vs 8-15
    const int lane = tid & 127;  // 16B column (128 * 16B = 2KB row)

    // ---- wave 0: scan of dur[b][0..511] entirely in registers + direct tok compute ----
    if (tid < 64) {
        const int4* __restrict__ d4 = reinterpret_cast<const int4*>(dur + b * LTOK);
        int4 a = d4[tid * 2];
        int4 c = d4[tid * 2 + 1];
        int p0 = a.x;
        int p1 = p0 + a.y;
        int p2 = p1 + a.z;
        int p3 = p2 + a.w;
        int p4 = p3 + c.x;
        int p5 = p4 + c.y;
        int p6 = p5 + c.z;
        int p7 = p6 + c.w;
        int s = p7;
        #pragma unroll
        for (int off = 1; off < 64; off <<= 1) {   // 64-lane inclusive shfl scan
            int n = __shfl_up(s, off, 64);
            if (tid >= off) s += n;
        }
        const int base = s - p7;                    // exclusive prefix of this lane's chunk
        // lane holds cumsum ends for tokens 8*tid .. 8*tid+7:
        const int e0 = base + p0, e1 = base + p1, e2 = base + p2, e3 = base + p3;
        const int e4 = base + p4, e5 = base + p5, e6 = base + p6, e7 = base + p7;
        const int tot = __shfl(s, 63, 64);
        if (tid == 63) stotal = s;

        if (t0 < tot) {
            // j(t) = #{ends <= t} summed over all 512 ends.
            // Pack two row-counts per 32-bit reg (sums <= 512, no field overflow).
            unsigned pk[8];
            #pragma unroll
            for (int rp = 0; rp < 8; ++rp) {
                const int ta = t0 + 2 * rp;
                const int tb = ta + 1;
                unsigned ca = (unsigned)((e0 <= ta) + (e1 <= ta) + (e2 <= ta) + (e3 <= ta) +
                                         (e4 <= ta) + (e5 <= ta) + (e6 <= ta) + (e7 <= ta));
                unsigned cb = (unsigned)((e0 <= tb) + (e1 <= tb) + (e2 <= tb) + (e3 <= tb) +
                                         (e4 <= tb) + (e5 <= tb) + (e6 <= tb) + (e7 <= tb));
                unsigned p = ca | (cb << 16);
                #pragma unroll
                for (int off = 32; off >= 1; off >>= 1)
                    p += (unsigned)__shfl_xor((int)p, off, 64);
                pk[rp] = p;
            }
            if (tid == 0) {
                #pragma unroll
                for (int rp = 0; rp < 8; ++rp) {
                    stok[2 * rp]     = (int)(pk[rp] & 0xffffu);
                    stok[2 * rp + 1] = (int)(pk[rp] >> 16);
                }
            }
        }
    }
    __syncthreads();

    const int total = stotal;
    f4v* __restrict__ ob =
        reinterpret_cast<f4v*>(out + ((size_t)b * TMAX + (size_t)t0) * DIM);

    // ---- fast path: block entirely in the zero tail -> plain streaming zero-fill ----
    if (t0 >= total) {
        #pragma unroll
        for (int i = 0; i < 8; ++i)
            ob[(size_t)(half * 8 + i) * (DIM / 4) + lane] = (f4v)0.f;
        return;
    }

    const f4v* __restrict__ xb =
        reinterpret_cast<const f4v*>(x + (size_t)b * LTOK * DIM);
    const int tbase = t0 + half * 8;

    // phase 1: all 8 token indices (LDS broadcast reads, independent)
    int j[8];
    #pragma unroll
    for (int i = 0; i < 8; ++i)
        j[i] = (tbase + i < total) ? stok[half * 8 + i] : -1;

    // phase 2: independent gather loads + plain stores
    #pragma unroll
    for (int i = 0; i < 8; ++i) {
        f4v v = (f4v)0.f;
        if (j[i] >= 0) v = xb[(size_t)j[i] * (DIM / 4) + lane];
        ob[(size_t)(half * 8 + i) * (DIM / 4) + lane] = v;
    }
}

extern "C" void kernel_launch(void* const* d_in, const int* in_sizes, int n_in,
                              void* d_out, int out_size, void* d_ws, size_t ws_size,
                              hipStream_t stream) {
    const float* x   = (const float*)d_in[0];        // [B, L, D] fp32
    const int*   dur = (const int*)d_in[1];          // [B, L] int32
    // d_in[2] = mel_max_length scalar (static 4096; hard-coded)
    float* out = (float*)d_out;                       // [B, TMAX, D] fp32

    MRTE_fused_kernel<<<dim3(TMAX / ROWS, BATCH), 256, 0, stream>>>(x, dur, out);
}